// Round 6
// baseline (191.286 us; speedup 1.0000x reference)
//
#include <hip/hip_runtime.h>
#include <stdint.h>

typedef float  f32x4 __attribute__((ext_vector_type(4)));
typedef int    i32x4 __attribute__((ext_vector_type(4)));
typedef short  bf16x8 __attribute__((ext_vector_type(8)));
typedef unsigned short u16;
typedef unsigned int   u32;

#define DEVINL __device__ __forceinline__

// fp32 -> bf16 RNE (scalar fallback for scatter stores)
DEVINL u16 f2bf(float f) {
  u32 u = __builtin_bit_cast(u32, f);
  u32 r = u + 0x7fffu + ((u >> 16) & 1u);
  return (u16)(r >> 16);
}

// packed fp32x2 -> bf16x2
DEVINL u32 cvtpk(float lo, float hi) {
  u32 r;
  asm("v_cvt_pk_bf16_f32 %0, %1, %2" : "=v"(r) : "v"(lo), "v"(hi));
  return r;
}

// D += A*B  (16x16x32 bf16 MFMA) — builtin so compiler handles hazards
DEVINL void mfma16(f32x4& d, i32x4 a, i32x4 b) {
  d = __builtin_amdgcn_mfma_f32_16x16x32_bf16(
      __builtin_bit_cast(bf16x8, a), __builtin_bit_cast(bf16x8, b), d, 0, 0, 0);
}

// async global->LDS, 16B per lane; LDS dest linear per wave (base + lane*16)
#define GLD16(gp, lp) __builtin_amdgcn_global_load_lds( \
    (__attribute__((address_space(1))) void*)(gp), \
    (__attribute__((address_space(3))) void*)(lp), 16, 0, 0)

// counted vmcnt wait + scheduling fence (rule #18)
#define VMW(n) do { asm volatile("s_waitcnt vmcnt(" #n ")" ::: "memory"); \
                    __builtin_amdgcn_sched_barrier(0); } while (0)
#define BAR() __builtin_amdgcn_s_barrier()

// one launch converting all three fp32 arrays to bf16
__global__ void cvt3_f32_bf16(const float* __restrict__ s0, u16* __restrict__ d0, int n0,
                              const float* __restrict__ s1, u16* __restrict__ d1, int n1,
                              const float* __restrict__ s2, u16* __restrict__ d2, int n2) {
  int i = blockIdx.x * blockDim.x + threadIdx.x;
  int stride = gridDim.x * blockDim.x;
  int nt = n0 + n1 + n2;
  for (; i < nt; i += stride) {
    const float* s; u16* d; int j = i;
    if (j < n0) { s = s0; d = d0; }
    else if ((j -= n0) < n1) { s = s1; d = d1; }
    else { j -= n1; s = s2; d = d2; }
    float4 v = ((const float4*)s)[j];
    ushort4 o;
    o.x = f2bf(v.x); o.y = f2bf(v.y); o.z = f2bf(v.z); o.w = f2bf(v.w);
    ((ushort4*)d)[j] = o;
  }
}

// ---------------------------------------------------------------------------
// gemm1: x[8192,768] * qkv_w[2304,768]^T -> QKV scatter.
// 256x256 tile, BK=64, 8 waves (512 thr), 4-phase counted-vmcnt pipeline.
// ALL four half-tiles of tile t+1 are first-used at t+1's P1 (waves span
// both halves), so: issue all 8 stage-loads early (P1: A0',B0'; P2: A1',B1'),
// wait VMW(4) @P3-end (oldest 4, 3 phases old) and VMW(0) @P4-end
// (youngest 4, 2-3 phases old) — provable: vmcnt(0)+BAR before nxt is read.
// ---------------------------------------------------------------------------
__global__ __launch_bounds__(512) void gemm_qkv_8p(
    const u16* __restrict__ A, const u16* __restrict__ Bw,
    const float* __restrict__ bias,
    u16* __restrict__ Qb, u16* __restrict__ Kb, u16* __restrict__ Vtb)
{
  constexpr int K = 768, T = 12;
  __shared__ __align__(16) unsigned char sm[131072];
  unsigned char* smA = sm;            // [2][8 planes][256 rows][16B]
  unsigned char* smB = sm + 65536;

  const int tid = threadIdx.x;
  const int l   = tid & 63;
  const int wid = tid >> 6;
  const int wm  = wid >> 2, wn = wid & 3;   // 2 x 4 wave grid
  const int g4  = l >> 4;
  const int c15 = l & 15;

  constexpr int ntiles = 9;           // N/256
  const int tile = ((int)blockIdx.x & 7) * 36 + ((int)blockIdx.x >> 3); // 288 = 8*36
  const int mbase = (tile / ntiles) * 256;
  const int nbase = (tile % ntiles) * 256;

  auto stA = [&](int bb, int kt, int h) {
    #pragma unroll
    for (int p = 0; p < 2; ++p) {
      int ch = p * 512 + tid;
      int row = ch & 127, pl = ch >> 7;
      GLD16(A + (size_t)(mbase + h * 128 + row) * K + kt * 64 + pl * 8,
            smA + bb * 32768 + (pl * 256 + h * 128 + row) * 16);
    }
  };
  auto stB = [&](int bb, int kt, int h) {
    #pragma unroll
    for (int p = 0; p < 2; ++p) {
      int ch = p * 512 + tid;
      int row = ch & 127, pl = ch >> 7;
      GLD16(Bw + (size_t)(nbase + h * 128 + row) * K + kt * 64 + pl * 8,
            smB + bb * 32768 + (pl * 256 + h * 128 + row) * 16);
    }
  };

  f32x4 acc[8][4] = {};
  i32x4 a[4][2], bq[2][2];

  // prologue: stage K-tile 0 fully; __syncthreads drains vmcnt(0)
  stA(0, 0, 0); stB(0, 0, 0); stB(0, 0, 1); stA(0, 0, 1);
  __syncthreads();

  for (int t = 0; t < T; ++t) {
    const int cur = t & 1, nxt = cur ^ 1;
    const bool pf = (t + 1 < T);
    unsigned char* cA = smA + cur * 32768;
    unsigned char* cB = smB + cur * 32768;

    // ---------- P1: acc[0..3][0..1] ----------
    #pragma unroll
    for (int i = 0; i < 4; ++i)
      #pragma unroll
      for (int ks = 0; ks < 2; ++ks)
        a[i][ks] = *(const i32x4*)(cA + ((ks * 4 + g4) * 256 + wm * 128 + i * 16 + c15) * 16);
    #pragma unroll
    for (int j = 0; j < 2; ++j)
      #pragma unroll
      for (int ks = 0; ks < 2; ++ks)
        bq[j][ks] = *(const i32x4*)(cB + ((ks * 4 + g4) * 256 + wn * 64 + j * 16 + c15) * 16);
    if (pf) { stA(nxt, t + 1, 0); stB(nxt, t + 1, 0); }
    BAR();
    __builtin_amdgcn_s_setprio(1);
    #pragma unroll
    for (int i = 0; i < 4; ++i)
      #pragma unroll
      for (int j = 0; j < 2; ++j)
        #pragma unroll
        for (int ks = 0; ks < 2; ++ks)
          mfma16(acc[i][j], a[i][ks], bq[j][ks]);
    __builtin_amdgcn_s_setprio(0);
    BAR();

    // ---------- P2: acc[0..3][2..3] ----------
    #pragma unroll
    for (int j = 0; j < 2; ++j)
      #pragma unroll
      for (int ks = 0; ks < 2; ++ks)
        bq[j][ks] = *(const i32x4*)(cB + ((ks * 4 + g4) * 256 + wn * 64 + 32 + j * 16 + c15) * 16);
    if (pf) { stA(nxt, t + 1, 1); stB(nxt, t + 1, 1); }
    BAR();
    __builtin_amdgcn_s_setprio(1);
    #pragma unroll
    for (int i = 0; i < 4; ++i)
      #pragma unroll
      for (int j = 0; j < 2; ++j)
        #pragma unroll
        for (int ks = 0; ks < 2; ++ks)
          mfma16(acc[i][2 + j], a[i][ks], bq[j][ks]);
    __builtin_amdgcn_s_setprio(0);
    BAR();

    // ---------- P3: acc[4..7][0..1] ----------
    #pragma unroll
    for (int i = 0; i < 4; ++i)
      #pragma unroll
      for (int ks = 0; ks < 2; ++ks)
        a[i][ks] = *(const i32x4*)(cA + ((ks * 4 + g4) * 256 + wm * 128 + 64 + i * 16 + c15) * 16);
    #pragma unroll
    for (int j = 0; j < 2; ++j)
      #pragma unroll
      for (int ks = 0; ks < 2; ++ks)
        bq[j][ks] = *(const i32x4*)(cB + ((ks * 4 + g4) * 256 + wn * 64 + j * 16 + c15) * 16);
    BAR();
    __builtin_amdgcn_s_setprio(1);
    #pragma unroll
    for (int i = 0; i < 4; ++i)
      #pragma unroll
      for (int j = 0; j < 2; ++j)
        #pragma unroll
        for (int ks = 0; ks < 2; ++ks)
          mfma16(acc[4 + i][j], a[i][ks], bq[j][ks]);
    __builtin_amdgcn_s_setprio(0);
    if (pf) { VMW(4); }   // oldest 4 (P1's stages, 3 phases old)
    BAR();

    // ---------- P4: acc[4..7][2..3] ----------
    #pragma unroll
    for (int j = 0; j < 2; ++j)
      #pragma unroll
      for (int ks = 0; ks < 2; ++ks)
        bq[j][ks] = *(const i32x4*)(cB + ((ks * 4 + g4) * 256 + wn * 64 + 32 + j * 16 + c15) * 16);
    BAR();
    __builtin_amdgcn_s_setprio(1);
    #pragma unroll
    for (int i = 0; i < 4; ++i)
      #pragma unroll
      for (int j = 0; j < 2; ++j)
        #pragma unroll
        for (int ks = 0; ks < 2; ++ks)
          mfma16(acc[4 + i][2 + j], a[i][ks], bq[j][ks]);
    __builtin_amdgcn_s_setprio(0);
    if (pf) { VMW(0); }   // youngest 4 (P2's stages, 2-3 phases old): nxt proven complete
    BAR();
  }

  // epilogue: QKV scatter (Q x0.125 -> [bh,p,d]; K -> [bh,p,d]; V -> V^T [bh,d,p])
  #pragma unroll
  for (int nj = 0; nj < 4; ++nj) {
    int n = nbase + wn * 64 + nj * 16 + c15;
    int which = n / 768;
    int rem = n - which * 768;
    int h = rem >> 6, d = rem & 63;
    float bv = bias[n];
    #pragma unroll
    for (int mi = 0; mi < 8; ++mi) {
      int m0 = mbase + wm * 128 + mi * 16 + g4 * 4;
      int b = m0 >> 10, p0 = m0 & 1023;
      int bh = b * 12 + h;
      if (which == 0) {
        u16* dst = Qb + ((size_t)bh * 1024 + p0) * 64 + d;
        #pragma unroll
        for (int jj = 0; jj < 4; ++jj) dst[(size_t)jj * 64] = f2bf((acc[mi][nj][jj] + bv) * 0.125f);
      } else if (which == 1) {
        u16* dst = Kb + ((size_t)bh * 1024 + p0) * 64 + d;
        #pragma unroll
        for (int jj = 0; jj < 4; ++jj) dst[(size_t)jj * 64] = f2bf(acc[mi][nj][jj] + bv);
      } else {
        uint2 uu;
        uu.x = cvtpk(acc[mi][nj][0] + bv, acc[mi][nj][1] + bv);
        uu.y = cvtpk(acc[mi][nj][2] + bv, acc[mi][nj][3] + bv);
        *(uint2*)(Vtb + ((size_t)bh * 64 + d) * 1024 + p0) = uu;
      }
    }
  }
}

// C = A * B^T (+bias), m97 2-phase structure — gemm2.
template<int BM, int BN, int FM, int FN>
__global__ __launch_bounds__(256) void gemm_bt(
    const u16* __restrict__ A, const u16* __restrict__ Bw,
    int M, int N, const float* __restrict__ bias, float* __restrict__ Cf)
{
  constexpr int BK = 32;
  constexpr int K  = 768;
  constexpr int ABYT = BM * BK * 2;
  constexpr int BBYT = BN * BK * 2;
  __shared__ __align__(16) unsigned char sm[2 * (ABYT + BBYT)];

  const int tid = threadIdx.x;
  const int l   = tid & 63;
  const int wid = tid >> 6;
  const int wm  = wid >> 1, wn = wid & 1;
  const int g4  = l >> 4;
  const int c15 = l & 15;

  const int ntiles = N / BN;
  const int wg  = ntiles * (M / BM);
  const int per = wg >> 3;
  const int tile = ((int)blockIdx.x & 7) * per + ((int)blockIdx.x >> 3);
  const int mbase = (tile / ntiles) * BM;
  const int nbase = (tile % ntiles) * BN;

  auto stage = [&](int buf, int kt) {
    unsigned char* ab = sm + buf * (ABYT + BBYT);
    unsigned char* bb = ab + ABYT;
    #pragma unroll
    for (int c = 0; c < BM / 64; ++c) {
      int ch = c * 256 + tid;
      int row = ch & (BM - 1), pl = ch / BM;
      GLD16(A + (size_t)(mbase + row) * K + kt * BK + pl * 8, ab + ch * 16);
    }
    #pragma unroll
    for (int c = 0; c < BN / 64; ++c) {
      int ch = c * 256 + tid;
      int row = ch & (BN - 1), pl = ch / BN;
      GLD16(Bw + (size_t)(nbase + row) * K + kt * BK + pl * 8, bb + ch * 16);
    }
  };

  f32x4 acc[FM][FN] = {};

  stage(0, 0);
  __syncthreads();

  for (int kt = 0; kt < K / BK; ++kt) {
    int cur = kt & 1;
    if (kt + 1 < K / BK) stage(cur ^ 1, kt + 1);
    unsigned char* ab = sm + cur * (ABYT + BBYT);
    unsigned char* bb = ab + ABYT;
    i32x4 af[FM], bf[FN];
    #pragma unroll
    for (int mt = 0; mt < FM; ++mt) {
      int row = wm * (BM / 2) + mt * 16 + c15;
      af[mt] = *(const i32x4*)(ab + (g4 * BM + row) * 16);
    }
    #pragma unroll
    for (int nt = 0; nt < FN; ++nt) {
      int row = wn * (BN / 2) + nt * 16 + c15;
      bf[nt] = *(const i32x4*)(bb + (g4 * BN + row) * 16);
    }
    __builtin_amdgcn_s_setprio(1);
    #pragma unroll
    for (int mt = 0; mt < FM; ++mt)
      #pragma unroll
      for (int nt = 0; nt < FN; ++nt)
        mfma16(acc[mt][nt], af[mt], bf[nt]);
    __builtin_amdgcn_s_setprio(0);
    __syncthreads();
  }

  #pragma unroll
  for (int nt = 0; nt < FN; ++nt) {
    int n = nbase + wn * (BN / 2) + nt * 16 + c15;
    float bv = bias[n];
    #pragma unroll
    for (int mt = 0; mt < FM; ++mt) {
      int m0 = mbase + wm * (BM / 2) + mt * 16 + g4 * 4;
      float* dst = Cf + (size_t)m0 * N + n;
      #pragma unroll
      for (int j = 0; j < 4; ++j) dst[(size_t)j * N] = acc[mt][nt][j] + bv;
    }
  }
}

// Flash attention (unchanged)
__global__ __launch_bounds__(256) void attn_fwd(
    const u16* __restrict__ Qb, const u16* __restrict__ Kb,
    const u16* __restrict__ Vtb, u16* __restrict__ Ob)
{
  __shared__ __align__(16) unsigned char sm[16384 + 4 * 8192];
  const int tid = threadIdx.x;
  const int l = tid & 63, wid = tid >> 6;
  const int g4 = l >> 4, c15 = l & 15;
  const int bid = blockIdx.x;
  const int bh = bid % 96, qt = bid / 96;

  const size_t bhoff = (size_t)bh * (1024 * 64);
  const u16* Qg = Qb + bhoff + (size_t)qt * 128 * 64;
  const u16* Kg = Kb + bhoff;
  const u16* Vg = Vtb + bhoff;

  #pragma unroll
  for (int c = 0; c < 4; ++c) {
    int ch = c * 256 + tid;
    int row = ch & 127, pl = ch >> 7;
    GLD16(Qg + (size_t)row * 64 + pl * 8, sm + ch * 16);
  }

  auto stageKV = [&](int buf, int t) {
    unsigned char* kb_ = sm + 16384 + buf * 8192;
    unsigned char* vb_ = sm + 32768 + buf * 8192;
    #pragma unroll
    for (int c = 0; c < 2; ++c) {
      int ch = c * 256 + tid;
      int row = ch & 63, pl = ch >> 6;
      GLD16(Kg + (size_t)(t * 64 + row) * 64 + pl * 8, kb_ + ch * 16);
      GLD16(Vg + (size_t)row * 1024 + t * 64 + pl * 8, vb_ + ch * 16);
    }
  };

  stageKV(0, 0);
  __syncthreads();

  i32x4 qf[2][2];
  #pragma unroll
  for (int qn = 0; qn < 2; ++qn)
    #pragma unroll
    for (int ks = 0; ks < 2; ++ks) {
      int row = wid * 32 + qn * 16 + c15;
      qf[qn][ks] = *(const i32x4*)(sm + ((ks * 4 + g4) * 128 + row) * 16);
    }
  __syncthreads();

  unsigned char* pw = sm + wid * 4096;

  const i32x4 ones = {0x3F803F80, 0x3F803F80, 0x3F803F80, 0x3F803F80};
  constexpr float LOG2E = 1.44269504f;

  f32x4 ot[4][2] = {};
  f32x4 lacc[2] = {};
  float mrow[2] = {-1e30f, -1e30f};
  float mc[2]   = {-1e30f, -1e30f};

  for (int t = 0; t < 16; ++t) {
    int cur = t & 1;
    if (t + 1 < 16) stageKV(cur ^ 1, t + 1);
    unsigned char* kb_ = sm + 16384 + cur * 8192;
    unsigned char* vb_ = sm + 32768 + cur * 8192;

    f32x4 st[4][2] = {};
    __builtin_amdgcn_s_setprio(1);
    #pragma unroll
    for (int ks = 0; ks < 2; ++ks)
      #pragma unroll
      for (int kmt = 0; kmt < 4; ++kmt) {
        i32x4 ka = *(const i32x4*)(kb_ + ((ks * 4 + g4) * 64 + kmt * 16 + c15) * 16);
        mfma16(st[kmt][0], ka, qf[0][ks]);
        mfma16(st[kmt][1], ka, qf[1][ks]);
      }
    __builtin_amdgcn_s_setprio(0);

    #pragma unroll
    for (int qn = 0; qn < 2; ++qn) {
      float mx = fmaxf(fmaxf(fmaxf(st[0][qn][0], st[0][qn][1]), fmaxf(st[0][qn][2], st[0][qn][3])),
                       fmaxf(fmaxf(st[1][qn][0], st[1][qn][1]), fmaxf(st[1][qn][2], st[1][qn][3])));
      mx = fmaxf(mx,
           fmaxf(fmaxf(fmaxf(st[2][qn][0], st[2][qn][1]), fmaxf(st[2][qn][2], st[2][qn][3])),
                 fmaxf(fmaxf(st[3][qn][0], st[3][qn][1]), fmaxf(st[3][qn][2], st[3][qn][3]))));
      mx = fmaxf(mx, __shfl_xor(mx, 16));
      mx = fmaxf(mx, __shfl_xor(mx, 32));
      if (!__all(mx - mrow[qn] <= 8.0f)) {
        float mnew = fmaxf(mrow[qn], mx);
        float sfq = exp2f((mrow[qn] - mnew) * LOG2E);
        mrow[qn] = mnew;
        mc[qn] = mnew * LOG2E;
        #pragma unroll
        for (int dmt = 0; dmt < 4; ++dmt)
          #pragma unroll
          for (int j = 0; j < 4; ++j) ot[dmt][qn][j] *= sfq;
        lacc[qn][0] *= sfq;
      }
      #pragma unroll
      for (int kmt = 0; kmt < 4; ++kmt) {
        float p0 = exp2f(__builtin_fmaf(st[kmt][qn][0], LOG2E, -mc[qn]));
        float p1 = exp2f(__builtin_fmaf(st[kmt][qn][1], LOG2E, -mc[qn]));
        float p2 = exp2f(__builtin_fmaf(st[kmt][qn][2], LOG2E, -mc[qn]));
        float p3 = exp2f(__builtin_fmaf(st[kmt][qn][3], LOG2E, -mc[qn]));
        int k0 = kmt * 16 + 4 * g4;
        uint2 ww;
        ww.x = cvtpk(p0, p1);
        ww.y = cvtpk(p2, p3);
        *(uint2*)(pw + ((k0 >> 3) * 32 + qn * 16 + c15) * 16 + (k0 & 7) * 2) = ww;
      }
    }

    i32x4 pb[2][2];
    #pragma unroll
    for (int qn = 0; qn < 2; ++qn)
      #pragma unroll
      for (int ks = 0; ks < 2; ++ks)
        pb[qn][ks] = *(const i32x4*)(pw + (((ks * 4 + g4) * 32) + qn * 16 + c15) * 16);

    __builtin_amdgcn_s_setprio(1);
    #pragma unroll
    for (int ks = 0; ks < 2; ++ks) {
      #pragma unroll
      for (int dmt = 0; dmt < 4; ++dmt) {
        i32x4 va = *(const i32x4*)(vb_ + ((ks * 4 + g4) * 64 + dmt * 16 + c15) * 16);
        mfma16(ot[dmt][0], va, pb[0][ks]);
        mfma16(ot[dmt][1], va, pb[1][ks]);
      }
      mfma16(lacc[0], ones, pb[0][ks]);
      mfma16(lacc[1], ones, pb[1][ks]);
    }
    __builtin_amdgcn_s_setprio(0);
    __syncthreads();
  }

  const int b = bh / 12, h = bh % 12;
  #pragma unroll
  for (int qn = 0; qn < 2; ++qn) {
    float inv = 1.0f / lacc[qn][0];
    int q = qt * 128 + wid * 32 + qn * 16 + c15;
    size_t rowoff = ((size_t)(b * 1024 + q) * 12 + h) * 64;
    #pragma unroll
    for (int dmt = 0; dmt < 4; ++dmt) {
      int d0 = dmt * 16 + g4 * 4;
      uint2 uu;
      uu.x = cvtpk(ot[dmt][qn][0] * inv, ot[dmt][qn][1] * inv);
      uu.y = cvtpk(ot[dmt][qn][2] * inv, ot[dmt][qn][3] * inv);
      *(uint2*)(Ob + rowoff + d0) = uu;
    }
  }
}

extern "C" void kernel_launch(void* const* d_in, const int* in_sizes, int n_in,
                              void* d_out, int out_size, void* d_ws, size_t ws_size,
                              hipStream_t stream) {
  const float* x    = (const float*)d_in[0];
  const float* qkvw = (const float*)d_in[1];
  const float* qkvb = (const float*)d_in[2];
  const float* outw = (const float*)d_in[3];
  const float* outb = (const float*)d_in[4];
  float* out = (float*)d_out;

  unsigned char* ws = (unsigned char*)d_ws;
  u16* xb  = (u16*)(ws);                          // 12.58 MB  [8192][768] bf16
  u16* wqb = (u16*)(ws + 12582912);               //  3.54 MB  [2304][768] bf16
  u16* wob = (u16*)(ws + 16121856);               //  1.18 MB  [768][768]  bf16
  u16* Qbf = (u16*)(ws + 17301504);               // 12.58 MB  [96][1024][64]
  u16* Kbf = (u16*)(ws + 29884416);               // 12.58 MB  [96][1024][64]
  u16* Vtb = (u16*)(ws + 42467328);               // 12.58 MB  [96][64][1024]
  u16* Ob  = xb;                                  // reuse x region (dead after gemm1)

  cvt3_f32_bf16<<<dim3(2048), dim3(256), 0, stream>>>(
      x, xb, 8192 * 768 / 4, qkvw, wqb, 2304 * 768 / 4, outw, wob, 768 * 768 / 4);

  gemm_qkv_8p<<<dim3(288), dim3(512), 0, stream>>>(
      xb, wqb, qkvb, Qbf, Kbf, Vtb);

  attn_fwd<<<dim3(768), dim3(256), 0, stream>>>(Qbf, Kbf, Vtb, Ob);

  gemm_bt<128, 64, 4, 2><<<dim3(768), dim3(256), 0, stream>>>(
      Ob, wob, 8192, 768, outb, out);
}

// Round 7
// 189.793 us; speedup vs baseline: 1.0079x; 1.0079x over previous
//
#include <hip/hip_runtime.h>
#include <stdint.h>

typedef float  f32x4 __attribute__((ext_vector_type(4)));
typedef int    i32x4 __attribute__((ext_vector_type(4)));
typedef short  bf16x8 __attribute__((ext_vector_type(8)));
typedef unsigned short u16;
typedef unsigned int   u32;

#define DEVINL __device__ __forceinline__

// fp32 -> bf16 RNE (scalar fallback for scatter stores)
DEVINL u16 f2bf(float f) {
  u32 u = __builtin_bit_cast(u32, f);
  u32 r = u + 0x7fffu + ((u >> 16) & 1u);
  return (u16)(r >> 16);
}

// packed fp32x2 -> bf16x2
DEVINL u32 cvtpk(float lo, float hi) {
  u32 r;
  asm("v_cvt_pk_bf16_f32 %0, %1, %2" : "=v"(r) : "v"(lo), "v"(hi));
  return r;
}

// D += A*B  (16x16x32 bf16 MFMA) — builtin so compiler handles hazards
DEVINL void mfma16(f32x4& d, i32x4 a, i32x4 b) {
  d = __builtin_amdgcn_mfma_f32_16x16x32_bf16(
      __builtin_bit_cast(bf16x8, a), __builtin_bit_cast(bf16x8, b), d, 0, 0, 0);
}

// async global->LDS, 16B per lane; LDS dest linear per wave (base + lane*16)
#define GLD16(gp, lp) __builtin_amdgcn_global_load_lds( \
    (__attribute__((address_space(1))) void*)(gp), \
    (__attribute__((address_space(3))) void*)(lp), 16, 0, 0)

// one launch converting all three fp32 arrays to bf16
__global__ void cvt3_f32_bf16(const float* __restrict__ s0, u16* __restrict__ d0, int n0,
                              const float* __restrict__ s1, u16* __restrict__ d1, int n1,
                              const float* __restrict__ s2, u16* __restrict__ d2, int n2) {
  int i = blockIdx.x * blockDim.x + threadIdx.x;
  int stride = gridDim.x * blockDim.x;
  int nt = n0 + n1 + n2;
  for (; i < nt; i += stride) {
    const float* s; u16* d; int j = i;
    if (j < n0) { s = s0; d = d0; }
    else if ((j -= n0) < n1) { s = s1; d = d1; }
    else { j -= n1; s = s2; d = d2; }
    float4 v = ((const float4*)s)[j];
    ushort4 o;
    o.x = f2bf(v.x); o.y = f2bf(v.y); o.z = f2bf(v.z); o.w = f2bf(v.w);
    ((ushort4*)d)[j] = o;
  }
}

// ---------------------------------------------------------------------------
// gemm1: x[8192,768] * qkv_w[2304,768]^T -> QKV scatter.
// 128x256 tile, BK=32, double-buffered 2-phase (m97 structure), 8 waves
// (2x4 grid, 64x64 per wave), 48KB LDS -> 2 blocks/CU (launch_bounds(512,4)),
// grid 576 (fine-grained -> tail ~1.13x, no lockstep rounds).
// ---------------------------------------------------------------------------
__global__ __launch_bounds__(512, 4) void gemm_qkv(
    const u16* __restrict__ A, const u16* __restrict__ Bw,
    const float* __restrict__ bias,
    u16* __restrict__ Qb, u16* __restrict__ Kb, u16* __restrict__ Vtb)
{
  constexpr int K = 768, T = 24;        // K-iters of BK=32
  __shared__ __align__(16) unsigned char sm[49152];
  unsigned char* smA = sm;              // [2 buf][4 planes][128 rows][16B] = 16KB
  unsigned char* smB = sm + 16384;      // [2 buf][4 planes][256 rows][16B] = 32KB

  const int tid = threadIdx.x;
  const int l   = tid & 63;
  const int wid = tid >> 6;
  const int wm  = wid >> 2, wn = wid & 3;   // 2 x 4 wave grid, 64x64 per wave
  const int g4  = l >> 4;
  const int c15 = l & 15;

  constexpr int ntiles = 9;             // N/256
  const int tile = ((int)blockIdx.x & 7) * 72 + ((int)blockIdx.x >> 3); // 576 = 8*72
  const int mbase = (tile / ntiles) * 128;
  const int nbase = (tile % ntiles) * 256;

  auto stage = [&](int buf, int kt) {
    // A: 8KB = 512 lanes x 16B, chunk = pl*128+row = tid bit-exact
    {
      int row = tid & 127, pl = tid >> 7;
      GLD16(A + (size_t)(mbase + row) * K + kt * 32 + pl * 8,
            smA + buf * 8192 + tid * 16);
    }
    // B: 16KB = 2 chunks
    #pragma unroll
    for (int c = 0; c < 2; ++c) {
      int ch = c * 512 + tid;
      int row = ch & 255, pl = ch >> 8;
      GLD16(Bw + (size_t)(nbase + row) * K + kt * 32 + pl * 8,
            smB + buf * 16384 + ch * 16);
    }
  };

  f32x4 acc[4][4] = {};

  stage(0, 0);
  __syncthreads();

  for (int kt = 0; kt < T; ++kt) {
    int cur = kt & 1;
    if (kt + 1 < T) stage(cur ^ 1, kt + 1);
    unsigned char* ab = smA + cur * 8192;
    unsigned char* bb = smB + cur * 16384;
    i32x4 af[4], bf[4];
    #pragma unroll
    for (int mt = 0; mt < 4; ++mt)
      af[mt] = *(const i32x4*)(ab + (g4 * 128 + wm * 64 + mt * 16 + c15) * 16);
    #pragma unroll
    for (int nt = 0; nt < 4; ++nt)
      bf[nt] = *(const i32x4*)(bb + (g4 * 256 + wn * 64 + nt * 16 + c15) * 16);
    __builtin_amdgcn_s_setprio(1);
    #pragma unroll
    for (int mt = 0; mt < 4; ++mt)
      #pragma unroll
      for (int nt = 0; nt < 4; ++nt)
        mfma16(acc[mt][nt], af[mt], bf[nt]);
    __builtin_amdgcn_s_setprio(0);
    __syncthreads();
  }

  // epilogue: QKV scatter (Q x0.125 -> [bh,p,d]; K -> [bh,p,d]; V -> V^T [bh,d,p])
  #pragma unroll
  for (int nt = 0; nt < 4; ++nt) {
    int n = nbase + wn * 64 + nt * 16 + c15;
    int which = n / 768;
    int rem = n - which * 768;
    int h = rem >> 6, d = rem & 63;
    float bv = bias[n];
    #pragma unroll
    for (int mt = 0; mt < 4; ++mt) {
      int m0 = mbase + wm * 64 + mt * 16 + g4 * 4;
      int b = m0 >> 10, p0 = m0 & 1023;
      int bh = b * 12 + h;
      if (which == 0) {
        u16* dst = Qb + ((size_t)bh * 1024 + p0) * 64 + d;
        #pragma unroll
        for (int jj = 0; jj < 4; ++jj) dst[(size_t)jj * 64] = f2bf((acc[mt][nt][jj] + bv) * 0.125f);
      } else if (which == 1) {
        u16* dst = Kb + ((size_t)bh * 1024 + p0) * 64 + d;
        #pragma unroll
        for (int jj = 0; jj < 4; ++jj) dst[(size_t)jj * 64] = f2bf(acc[mt][nt][jj] + bv);
      } else {
        uint2 uu;
        uu.x = cvtpk(acc[mt][nt][0] + bv, acc[mt][nt][1] + bv);
        uu.y = cvtpk(acc[mt][nt][2] + bv, acc[mt][nt][3] + bv);
        *(uint2*)(Vtb + ((size_t)bh * 64 + d) * 1024 + p0) = uu;
      }
    }
  }
}

// C = A * B^T (+bias), m97 2-phase structure — gemm2.
template<int BM, int BN, int FM, int FN>
__global__ __launch_bounds__(256) void gemm_bt(
    const u16* __restrict__ A, const u16* __restrict__ Bw,
    int M, int N, const float* __restrict__ bias, float* __restrict__ Cf)
{
  constexpr int BK = 32;
  constexpr int K  = 768;
  constexpr int ABYT = BM * BK * 2;
  constexpr int BBYT = BN * BK * 2;
  __shared__ __align__(16) unsigned char sm[2 * (ABYT + BBYT)];

  const int tid = threadIdx.x;
  const int l   = tid & 63;
  const int wid = tid >> 6;
  const int wm  = wid >> 1, wn = wid & 1;
  const int g4  = l >> 4;
  const int c15 = l & 15;

  const int ntiles = N / BN;
  const int wg  = ntiles * (M / BM);
  const int per = wg >> 3;
  const int tile = ((int)blockIdx.x & 7) * per + ((int)blockIdx.x >> 3);
  const int mbase = (tile / ntiles) * BM;
  const int nbase = (tile % ntiles) * BN;

  auto stage = [&](int buf, int kt) {
    unsigned char* ab = sm + buf * (ABYT + BBYT);
    unsigned char* bb = ab + ABYT;
    #pragma unroll
    for (int c = 0; c < BM / 64; ++c) {
      int ch = c * 256 + tid;
      int row = ch & (BM - 1), pl = ch / BM;
      GLD16(A + (size_t)(mbase + row) * K + kt * BK + pl * 8, ab + ch * 16);
    }
    #pragma unroll
    for (int c = 0; c < BN / 64; ++c) {
      int ch = c * 256 + tid;
      int row = ch & (BN - 1), pl = ch / BN;
      GLD16(Bw + (size_t)(nbase + row) * K + kt * BK + pl * 8, bb + ch * 16);
    }
  };

  f32x4 acc[FM][FN] = {};

  stage(0, 0);
  __syncthreads();

  for (int kt = 0; kt < K / BK; ++kt) {
    int cur = kt & 1;
    if (kt + 1 < K / BK) stage(cur ^ 1, kt + 1);
    unsigned char* ab = sm + cur * (ABYT + BBYT);
    unsigned char* bb = ab + ABYT;
    i32x4 af[FM], bf[FN];
    #pragma unroll
    for (int mt = 0; mt < FM; ++mt) {
      int row = wm * (BM / 2) + mt * 16 + c15;
      af[mt] = *(const i32x4*)(ab + (g4 * BM + row) * 16);
    }
    #pragma unroll
    for (int nt = 0; nt < FN; ++nt) {
      int row = wn * (BN / 2) + nt * 16 + c15;
      bf[nt] = *(const i32x4*)(bb + (g4 * BN + row) * 16);
    }
    __builtin_amdgcn_s_setprio(1);
    #pragma unroll
    for (int mt = 0; mt < FM; ++mt)
      #pragma unroll
      for (int nt = 0; nt < FN; ++nt)
        mfma16(acc[mt][nt], af[mt], bf[nt]);
    __builtin_amdgcn_s_setprio(0);
    __syncthreads();
  }

  #pragma unroll
  for (int nt = 0; nt < FN; ++nt) {
    int n = nbase + wn * (BN / 2) + nt * 16 + c15;
    float bv = bias[n];
    #pragma unroll
    for (int mt = 0; mt < FM; ++mt) {
      int m0 = mbase + wm * (BM / 2) + mt * 16 + g4 * 4;
      float* dst = Cf + (size_t)m0 * N + n;
      #pragma unroll
      for (int j = 0; j < 4; ++j) dst[(size_t)j * N] = acc[mt][nt][j] + bv;
    }
  }
}

// Flash attention (unchanged)
__global__ __launch_bounds__(256) void attn_fwd(
    const u16* __restrict__ Qb, const u16* __restrict__ Kb,
    const u16* __restrict__ Vtb, u16* __restrict__ Ob)
{
  __shared__ __align__(16) unsigned char sm[16384 + 4 * 8192];
  const int tid = threadIdx.x;
  const int l = tid & 63, wid = tid >> 6;
  const int g4 = l >> 4, c15 = l & 15;
  const int bid = blockIdx.x;
  const int bh = bid % 96, qt = bid / 96;

  const size_t bhoff = (size_t)bh * (1024 * 64);
  const u16* Qg = Qb + bhoff + (size_t)qt * 128 * 64;
  const u16* Kg = Kb + bhoff;
  const u16* Vg = Vtb + bhoff;

  #pragma unroll
  for (int c = 0; c < 4; ++c) {
    int ch = c * 256 + tid;
    int row = ch & 127, pl = ch >> 7;
    GLD16(Qg + (size_t)row * 64 + pl * 8, sm + ch * 16);
  }

  auto stageKV = [&](int buf, int t) {
    unsigned char* kb_ = sm + 16384 + buf * 8192;
    unsigned char* vb_ = sm + 32768 + buf * 8192;
    #pragma unroll
    for (int c = 0; c < 2; ++c) {
      int ch = c * 256 + tid;
      int row = ch & 63, pl = ch >> 6;
      GLD16(Kg + (size_t)(t * 64 + row) * 64 + pl * 8, kb_ + ch * 16);
      GLD16(Vg + (size_t)row * 1024 + t * 64 + pl * 8, vb_ + ch * 16);
    }
  };

  stageKV(0, 0);
  __syncthreads();

  i32x4 qf[2][2];
  #pragma unroll
  for (int qn = 0; qn < 2; ++qn)
    #pragma unroll
    for (int ks = 0; ks < 2; ++ks) {
      int row = wid * 32 + qn * 16 + c15;
      qf[qn][ks] = *(const i32x4*)(sm + ((ks * 4 + g4) * 128 + row) * 16);
    }
  __syncthreads();

  unsigned char* pw = sm + wid * 4096;

  const i32x4 ones = {0x3F803F80, 0x3F803F80, 0x3F803F80, 0x3F803F80};
  constexpr float LOG2E = 1.44269504f;

  f32x4 ot[4][2] = {};
  f32x4 lacc[2] = {};
  float mrow[2] = {-1e30f, -1e30f};
  float mc[2]   = {-1e30f, -1e30f};

  for (int t = 0; t < 16; ++t) {
    int cur = t & 1;
    if (t + 1 < 16) stageKV(cur ^ 1, t + 1);
    unsigned char* kb_ = sm + 16384 + cur * 8192;
    unsigned char* vb_ = sm + 32768 + cur * 8192;

    f32x4 st[4][2] = {};
    __builtin_amdgcn_s_setprio(1);
    #pragma unroll
    for (int ks = 0; ks < 2; ++ks)
      #pragma unroll
      for (int kmt = 0; kmt < 4; ++kmt) {
        i32x4 ka = *(const i32x4*)(kb_ + ((ks * 4 + g4) * 64 + kmt * 16 + c15) * 16);
        mfma16(st[kmt][0], ka, qf[0][ks]);
        mfma16(st[kmt][1], ka, qf[1][ks]);
      }
    __builtin_amdgcn_s_setprio(0);

    #pragma unroll
    for (int qn = 0; qn < 2; ++qn) {
      float mx = fmaxf(fmaxf(fmaxf(st[0][qn][0], st[0][qn][1]), fmaxf(st[0][qn][2], st[0][qn][3])),
                       fmaxf(fmaxf(st[1][qn][0], st[1][qn][1]), fmaxf(st[1][qn][2], st[1][qn][3])));
      mx = fmaxf(mx,
           fmaxf(fmaxf(fmaxf(st[2][qn][0], st[2][qn][1]), fmaxf(st[2][qn][2], st[2][qn][3])),
                 fmaxf(fmaxf(st[3][qn][0], st[3][qn][1]), fmaxf(st[3][qn][2], st[3][qn][3]))));
      mx = fmaxf(mx, __shfl_xor(mx, 16));
      mx = fmaxf(mx, __shfl_xor(mx, 32));
      if (!__all(mx - mrow[qn] <= 8.0f)) {
        float mnew = fmaxf(mrow[qn], mx);
        float sfq = exp2f((mrow[qn] - mnew) * LOG2E);
        mrow[qn] = mnew;
        mc[qn] = mnew * LOG2E;
        #pragma unroll
        for (int dmt = 0; dmt < 4; ++dmt)
          #pragma unroll
          for (int j = 0; j < 4; ++j) ot[dmt][qn][j] *= sfq;
        lacc[qn][0] *= sfq;
      }
      #pragma unroll
      for (int kmt = 0; kmt < 4; ++kmt) {
        float p0 = exp2f(__builtin_fmaf(st[kmt][qn][0], LOG2E, -mc[qn]));
        float p1 = exp2f(__builtin_fmaf(st[kmt][qn][1], LOG2E, -mc[qn]));
        float p2 = exp2f(__builtin_fmaf(st[kmt][qn][2], LOG2E, -mc[qn]));
        float p3 = exp2f(__builtin_fmaf(st[kmt][qn][3], LOG2E, -mc[qn]));
        int k0 = kmt * 16 + 4 * g4;
        uint2 ww;
        ww.x = cvtpk(p0, p1);
        ww.y = cvtpk(p2, p3);
        *(uint2*)(pw + ((k0 >> 3) * 32 + qn * 16 + c15) * 16 + (k0 & 7) * 2) = ww;
      }
    }

    i32x4 pb[2][2];
    #pragma unroll
    for (int qn = 0; qn < 2; ++qn)
      #pragma unroll
      for (int ks = 0; ks < 2; ++ks)
        pb[qn][ks] = *(const i32x4*)(pw + (((ks * 4 + g4) * 32) + qn * 16 + c15) * 16);

    __builtin_amdgcn_s_setprio(1);
    #pragma unroll
    for (int ks = 0; ks < 2; ++ks) {
      #pragma unroll
      for (int dmt = 0; dmt < 4; ++dmt) {
        i32x4 va = *(const i32x4*)(vb_ + ((ks * 4 + g4) * 64 + dmt * 16 + c15) * 16);
        mfma16(ot[dmt][0], va, pb[0][ks]);
        mfma16(ot[dmt][1], va, pb[1][ks]);
      }
      mfma16(lacc[0], ones, pb[0][ks]);
      mfma16(lacc[1], ones, pb[1][ks]);
    }
    __builtin_amdgcn_s_setprio(0);
    __syncthreads();
  }

  const int b = bh / 12, h = bh % 12;
  #pragma unroll
  for (int qn = 0; qn < 2; ++qn) {
    float inv = 1.0f / lacc[qn][0];
    int q = qt * 128 + wid * 32 + qn * 16 + c15;
    size_t rowoff = ((size_t)(b * 1024 + q) * 12 + h) * 64;
    #pragma unroll
    for (int dmt = 0; dmt < 4; ++dmt) {
      int d0 = dmt * 16 + g4 * 4;
      uint2 uu;
      uu.x = cvtpk(ot[dmt][qn][0] * inv, ot[dmt][qn][1] * inv);
      uu.y = cvtpk(ot[dmt][qn][2] * inv, ot[dmt][qn][3] * inv);
      *(uint2*)(Ob + rowoff + d0) = uu;
    }
  }
}

extern "C" void kernel_launch(void* const* d_in, const int* in_sizes, int n_in,
                              void* d_out, int out_size, void* d_ws, size_t ws_size,
                              hipStream_t stream) {
  const float* x    = (const float*)d_in[0];
  const float* qkvw = (const float*)d_in[1];
  const float* qkvb = (const float*)d_in[2];
  const float* outw = (const float*)d_in[3];
  const float* outb = (const float*)d_in[4];
  float* out = (float*)d_out;

  unsigned char* ws = (unsigned char*)d_ws;
  u16* xb  = (u16*)(ws);                          // 12.58 MB  [8192][768] bf16
  u16* wqb = (u16*)(ws + 12582912);               //  3.54 MB  [2304][768] bf16
  u16* wob = (u16*)(ws + 16121856);               //  1.18 MB  [768][768]  bf16
  u16* Qbf = (u16*)(ws + 17301504);               // 12.58 MB  [96][1024][64]
  u16* Kbf = (u16*)(ws + 29884416);               // 12.58 MB  [96][1024][64]
  u16* Vtb = (u16*)(ws + 42467328);               // 12.58 MB  [96][64][1024]
  u16* Ob  = xb;                                  // reuse x region (dead after gemm1)

  cvt3_f32_bf16<<<dim3(2048), dim3(256), 0, stream>>>(
      x, xb, 8192 * 768 / 4, qkvw, wqb, 2304 * 768 / 4, outw, wob, 768 * 768 / 4);

  gemm_qkv<<<dim3(576), dim3(512), 0, stream>>>(
      xb, wqb, qkvb, Qbf, Kbf, Vtb);

  attn_fwd<<<dim3(768), dim3(256), 0, stream>>>(Qbf, Kbf, Vtb, Ob);

  gemm_bt<128, 64, 4, 2><<<dim3(768), dim3(256), 0, stream>>>(
      Ob, wob, 8192, 768, outb, out);
}

// Round 8
// 179.075 us; speedup vs baseline: 1.0682x; 1.0599x over previous
//
#include <hip/hip_runtime.h>
#include <stdint.h>

typedef float  f32x4 __attribute__((ext_vector_type(4)));
typedef int    i32x4 __attribute__((ext_vector_type(4)));
typedef short  bf16x8 __attribute__((ext_vector_type(8)));
typedef unsigned short u16;
typedef unsigned int   u32;

#define DEVINL __device__ __forceinline__

// fp32 -> bf16 RNE (scalar fallback for scatter stores)
DEVINL u16 f2bf(float f) {
  u32 u = __builtin_bit_cast(u32, f);
  u32 r = u + 0x7fffu + ((u >> 16) & 1u);
  return (u16)(r >> 16);
}

// packed fp32x2 -> bf16x2
DEVINL u32 cvtpk(float lo, float hi) {
  u32 r;
  asm("v_cvt_pk_bf16_f32 %0, %1, %2" : "=v"(r) : "v"(lo), "v"(hi));
  return r;
}

// D += A*B  (16x16x32 bf16 MFMA)
DEVINL void mfma16(f32x4& d, i32x4 a, i32x4 b) {
  d = __builtin_amdgcn_mfma_f32_16x16x32_bf16(
      __builtin_bit_cast(bf16x8, a), __builtin_bit_cast(bf16x8, b), d, 0, 0, 0);
}

// async global->LDS, 16B per lane; LDS dest linear per wave (base + lane*16)
#define GLD16(gp, lp) __builtin_amdgcn_global_load_lds( \
    (__attribute__((address_space(1))) void*)(gp), \
    (__attribute__((address_space(3))) void*)(lp), 16, 0, 0)

#define BAR() do { __builtin_amdgcn_s_barrier(); \
                   __builtin_amdgcn_sched_barrier(0); } while (0)

// counted vmcnt wait + scheduling fence (rule #18)
template<int N> DEVINL void vmwait() {
  static_assert(N == 0 || N == 3 || N == 4, "literal vmcnt only");
  if constexpr (N == 0) asm volatile("s_waitcnt vmcnt(0)" ::: "memory");
  else if constexpr (N == 3) asm volatile("s_waitcnt vmcnt(3)" ::: "memory");
  else                       asm volatile("s_waitcnt vmcnt(4)" ::: "memory");
  __builtin_amdgcn_sched_barrier(0);
}

// one launch converting all three fp32 arrays to bf16
__global__ void cvt3_f32_bf16(const float* __restrict__ s0, u16* __restrict__ d0, int n0,
                              const float* __restrict__ s1, u16* __restrict__ d1, int n1,
                              const float* __restrict__ s2, u16* __restrict__ d2, int n2) {
  int i = blockIdx.x * blockDim.x + threadIdx.x;
  int stride = gridDim.x * blockDim.x;
  int nt = n0 + n1 + n2;
  for (; i < nt; i += stride) {
    const float* s; u16* d; int j = i;
    if (j < n0) { s = s0; d = d0; }
    else if ((j -= n0) < n1) { s = s1; d = d1; }
    else { j -= n1; s = s2; d = d2; }
    float4 v = ((const float4*)s)[j];
    ushort4 o;
    o.x = f2bf(v.x); o.y = f2bf(v.y); o.z = f2bf(v.z); o.w = f2bf(v.w);
    ((ushort4*)d)[j] = o;
  }
}

// ---------------------------------------------------------------------------
// C = A * B^T (+bias). Triple-buffered LDS + counted vmcnt (T4 graft):
// iter t reads buf t%3, stages buf (t+2)%3, ends with vmcnt(NL)+s_barrier
// (NOT __syncthreads' vmcnt(0) drain) -> loads get ~2 iters of latency cover.
// Safety: reads of buf b complete (lgkm consumed by MFMA) before the barrier
// after which b is re-staged; vmcnt(NL) at end of t proves buf t+1 landed.
// EPI==0: fp32 C + bias.  EPI==1: QKV scatter (Q x0.125, K, V^T).
// ---------------------------------------------------------------------------
template<int BM, int BN, int FM, int FN, int EPI>
__global__ __launch_bounds__(256) void gemm_bt(
    const u16* __restrict__ A, const u16* __restrict__ Bw,
    int M, int N, const float* __restrict__ bias,
    float* __restrict__ Cf, u16* __restrict__ Qb, u16* __restrict__ Kb, u16* __restrict__ Vtb)
{
  constexpr int BK = 32;
  constexpr int K  = 768;
  constexpr int T  = K / BK;          // 24
  constexpr int ABYT = BM * BK * 2;   // bytes per A buf
  constexpr int BBYT = BN * BK * 2;
  constexpr int BUF  = ABYT + BBYT;
  constexpr int NL   = (BM + BN) / 64; // GLD16 per thread per stage
  __shared__ __align__(16) unsigned char sm[3 * BUF];

  const int tid = threadIdx.x;
  const int l   = tid & 63;
  const int wid = tid >> 6;
  const int wm  = wid >> 1, wn = wid & 1;
  const int g4  = l >> 4;
  const int c15 = l & 15;

  const int ntiles = N / BN;
  const int wg  = ntiles * (M / BM);
  const int per = wg >> 3;
  const int tile = ((int)blockIdx.x & 7) * per + ((int)blockIdx.x >> 3); // XCD-contiguous
  const int mbase = (tile / ntiles) * BM;
  const int nbase = (tile % ntiles) * BN;

  auto stage = [&](int buf, int kt) {
    unsigned char* ab = sm + buf * BUF;
    unsigned char* bb = ab + ABYT;
    #pragma unroll
    for (int c = 0; c < BM / 64; ++c) {
      int ch = c * 256 + tid;
      int row = ch & (BM - 1), pl = ch / BM;
      GLD16(A + (size_t)(mbase + row) * K + kt * BK + pl * 8, ab + ch * 16);
    }
    #pragma unroll
    for (int c = 0; c < BN / 64; ++c) {
      int ch = c * 256 + tid;
      int row = ch & (BN - 1), pl = ch / BN;
      GLD16(Bw + (size_t)(nbase + row) * K + kt * BK + pl * 8, bb + ch * 16);
    }
  };

  f32x4 acc[FM][FN] = {};

  // prologue: stage bufs 0,1; wait buf0 (allow buf1 in flight)
  stage(0, 0);
  stage(1, 1);
  vmwait<NL>();
  BAR();

  int cb = 0, sb = 2;
  for (int t = 0; t < T; ++t) {
    unsigned char* ab = sm + cb * BUF;
    unsigned char* bb = ab + ABYT;
    i32x4 af[FM], bf[FN];
    #pragma unroll
    for (int mt = 0; mt < FM; ++mt) {
      int row = wm * (BM / 2) + mt * 16 + c15;
      af[mt] = *(const i32x4*)(ab + (g4 * BM + row) * 16);
    }
    #pragma unroll
    for (int nt = 0; nt < FN; ++nt) {
      int row = wn * (BN / 2) + nt * 16 + c15;
      bf[nt] = *(const i32x4*)(bb + (g4 * BN + row) * 16);
    }
    if (t + 2 < T) stage(sb, t + 2);
    __builtin_amdgcn_s_setprio(1);
    #pragma unroll
    for (int mt = 0; mt < FM; ++mt)
      #pragma unroll
      for (int nt = 0; nt < FN; ++nt)
        mfma16(acc[mt][nt], af[mt], bf[nt]);
    __builtin_amdgcn_s_setprio(0);
    if (t < T - 2)       vmwait<NL>();  // buf t+1 proven complete
    else if (t == T - 2) vmwait<0>();   // last buf proven complete
    if (t + 1 < T) BAR();
    cb = (cb == 2) ? 0 : cb + 1;
    sb = (sb == 2) ? 0 : sb + 1;
  }

  if constexpr (EPI == 0) {
    #pragma unroll
    for (int nt = 0; nt < FN; ++nt) {
      int n = nbase + wn * (BN / 2) + nt * 16 + c15;
      float bv = bias[n];
      #pragma unroll
      for (int mt = 0; mt < FM; ++mt) {
        int m0 = mbase + wm * (BM / 2) + mt * 16 + g4 * 4;
        float* dst = Cf + (size_t)m0 * N + n;
        #pragma unroll
        for (int j = 0; j < 4; ++j) dst[(size_t)j * N] = acc[mt][nt][j] + bv;
      }
    }
  } else {
    #pragma unroll
    for (int nt = 0; nt < FN; ++nt) {
      int n = nbase + wn * (BN / 2) + nt * 16 + c15;
      int which = n / 768;
      int rem = n - which * 768;
      int h = rem >> 6, d = rem & 63;
      float bv = bias[n];
      #pragma unroll
      for (int mt = 0; mt < FM; ++mt) {
        int m0 = mbase + wm * (BM / 2) + mt * 16 + g4 * 4;
        int b = m0 >> 10, p0 = m0 & 1023;
        int bh = b * 12 + h;
        if (which == 0) {
          u16* dst = Qb + ((size_t)bh * 1024 + p0) * 64 + d;
          #pragma unroll
          for (int jj = 0; jj < 4; ++jj) dst[(size_t)jj * 64] = f2bf((acc[mt][nt][jj] + bv) * 0.125f);
        } else if (which == 1) {
          u16* dst = Kb + ((size_t)bh * 1024 + p0) * 64 + d;
          #pragma unroll
          for (int jj = 0; jj < 4; ++jj) dst[(size_t)jj * 64] = f2bf(acc[mt][nt][jj] + bv);
        } else {
          uint2 uu;
          uu.x = cvtpk(acc[mt][nt][0] + bv, acc[mt][nt][1] + bv);
          uu.y = cvtpk(acc[mt][nt][2] + bv, acc[mt][nt][3] + bv);
          *(uint2*)(Vtb + ((size_t)bh * 64 + d) * 1024 + p0) = uu;
        }
      }
    }
  }
}

// Flash attention (unchanged)
__global__ __launch_bounds__(256) void attn_fwd(
    const u16* __restrict__ Qb, const u16* __restrict__ Kb,
    const u16* __restrict__ Vtb, u16* __restrict__ Ob)
{
  __shared__ __align__(16) unsigned char sm[16384 + 4 * 8192];
  const int tid = threadIdx.x;
  const int l = tid & 63, wid = tid >> 6;
  const int g4 = l >> 4, c15 = l & 15;
  const int bid = blockIdx.x;
  const int bh = bid % 96, qt = bid / 96;

  const size_t bhoff = (size_t)bh * (1024 * 64);
  const u16* Qg = Qb + bhoff + (size_t)qt * 128 * 64;
  const u16* Kg = Kb + bhoff;
  const u16* Vg = Vtb + bhoff;

  #pragma unroll
  for (int c = 0; c < 4; ++c) {
    int ch = c * 256 + tid;
    int row = ch & 127, pl = ch >> 7;
    GLD16(Qg + (size_t)row * 64 + pl * 8, sm + ch * 16);
  }

  auto stageKV = [&](int buf, int t) {
    unsigned char* kb_ = sm + 16384 + buf * 8192;
    unsigned char* vb_ = sm + 32768 + buf * 8192;
    #pragma unroll
    for (int c = 0; c < 2; ++c) {
      int ch = c * 256 + tid;
      int row = ch & 63, pl = ch >> 6;
      GLD16(Kg + (size_t)(t * 64 + row) * 64 + pl * 8, kb_ + ch * 16);
      GLD16(Vg + (size_t)row * 1024 + t * 64 + pl * 8, vb_ + ch * 16);
    }
  };

  stageKV(0, 0);
  __syncthreads();

  i32x4 qf[2][2];
  #pragma unroll
  for (int qn = 0; qn < 2; ++qn)
    #pragma unroll
    for (int ks = 0; ks < 2; ++ks) {
      int row = wid * 32 + qn * 16 + c15;
      qf[qn][ks] = *(const i32x4*)(sm + ((ks * 4 + g4) * 128 + row) * 16);
    }
  __syncthreads();

  unsigned char* pw = sm + wid * 4096;

  const i32x4 ones = {0x3F803F80, 0x3F803F80, 0x3F803F80, 0x3F803F80};
  constexpr float LOG2E = 1.44269504f;

  f32x4 ot[4][2] = {};
  f32x4 lacc[2] = {};
  float mrow[2] = {-1e30f, -1e30f};
  float mc[2]   = {-1e30f, -1e30f};

  for (int t = 0; t < 16; ++t) {
    int cur = t & 1;
    if (t + 1 < 16) stageKV(cur ^ 1, t + 1);
    unsigned char* kb_ = sm + 16384 + cur * 8192;
    unsigned char* vb_ = sm + 32768 + cur * 8192;

    f32x4 st[4][2] = {};
    __builtin_amdgcn_s_setprio(1);
    #pragma unroll
    for (int ks = 0; ks < 2; ++ks)
      #pragma unroll
      for (int kmt = 0; kmt < 4; ++kmt) {
        i32x4 ka = *(const i32x4*)(kb_ + ((ks * 4 + g4) * 64 + kmt * 16 + c15) * 16);
        mfma16(st[kmt][0], ka, qf[0][ks]);
        mfma16(st[kmt][1], ka, qf[1][ks]);
      }
    __builtin_amdgcn_s_setprio(0);

    #pragma unroll
    for (int qn = 0; qn < 2; ++qn) {
      float mx = fmaxf(fmaxf(fmaxf(st[0][qn][0], st[0][qn][1]), fmaxf(st[0][qn][2], st[0][qn][3])),
                       fmaxf(fmaxf(st[1][qn][0], st[1][qn][1]), fmaxf(st[1][qn][2], st[1][qn][3])));
      mx = fmaxf(mx,
           fmaxf(fmaxf(fmaxf(st[2][qn][0], st[2][qn][1]), fmaxf(st[2][qn][2], st[2][qn][3])),
                 fmaxf(fmaxf(st[3][qn][0], st[3][qn][1]), fmaxf(st[3][qn][2], st[3][qn][3]))));
      mx = fmaxf(mx, __shfl_xor(mx, 16));
      mx = fmaxf(mx, __shfl_xor(mx, 32));
      if (!__all(mx - mrow[qn] <= 8.0f)) {
        float mnew = fmaxf(mrow[qn], mx);
        float sfq = exp2f((mrow[qn] - mnew) * LOG2E);
        mrow[qn] = mnew;
        mc[qn] = mnew * LOG2E;
        #pragma unroll
        for (int dmt = 0; dmt < 4; ++dmt)
          #pragma unroll
          for (int j = 0; j < 4; ++j) ot[dmt][qn][j] *= sfq;
        lacc[qn][0] *= sfq;
      }
      #pragma unroll
      for (int kmt = 0; kmt < 4; ++kmt) {
        float p0 = exp2f(__builtin_fmaf(st[kmt][qn][0], LOG2E, -mc[qn]));
        float p1 = exp2f(__builtin_fmaf(st[kmt][qn][1], LOG2E, -mc[qn]));
        float p2 = exp2f(__builtin_fmaf(st[kmt][qn][2], LOG2E, -mc[qn]));
        float p3 = exp2f(__builtin_fmaf(st[kmt][qn][3], LOG2E, -mc[qn]));
        int k0 = kmt * 16 + 4 * g4;
        uint2 ww;
        ww.x = cvtpk(p0, p1);
        ww.y = cvtpk(p2, p3);
        *(uint2*)(pw + ((k0 >> 3) * 32 + qn * 16 + c15) * 16 + (k0 & 7) * 2) = ww;
      }
    }

    i32x4 pb[2][2];
    #pragma unroll
    for (int qn = 0; qn < 2; ++qn)
      #pragma unroll
      for (int ks = 0; ks < 2; ++ks)
        pb[qn][ks] = *(const i32x4*)(pw + (((ks * 4 + g4) * 32) + qn * 16 + c15) * 16);

    __builtin_amdgcn_s_setprio(1);
    #pragma unroll
    for (int ks = 0; ks < 2; ++ks) {
      #pragma unroll
      for (int dmt = 0; dmt < 4; ++dmt) {
        i32x4 va = *(const i32x4*)(vb_ + ((ks * 4 + g4) * 64 + dmt * 16 + c15) * 16);
        mfma16(ot[dmt][0], va, pb[0][ks]);
        mfma16(ot[dmt][1], va, pb[1][ks]);
      }
      mfma16(lacc[0], ones, pb[0][ks]);
      mfma16(lacc[1], ones, pb[1][ks]);
    }
    __builtin_amdgcn_s_setprio(0);
    __syncthreads();
  }

  const int b = bh / 12, h = bh % 12;
  #pragma unroll
  for (int qn = 0; qn < 2; ++qn) {
    float inv = 1.0f / lacc[qn][0];
    int q = qt * 128 + wid * 32 + qn * 16 + c15;
    size_t rowoff = ((size_t)(b * 1024 + q) * 12 + h) * 64;
    #pragma unroll
    for (int dmt = 0; dmt < 4; ++dmt) {
      int d0 = dmt * 16 + g4 * 4;
      uint2 uu;
      uu.x = cvtpk(ot[dmt][qn][0] * inv, ot[dmt][qn][1] * inv);
      uu.y = cvtpk(ot[dmt][qn][2] * inv, ot[dmt][qn][3] * inv);
      *(uint2*)(Ob + rowoff + d0) = uu;
    }
  }
}

extern "C" void kernel_launch(void* const* d_in, const int* in_sizes, int n_in,
                              void* d_out, int out_size, void* d_ws, size_t ws_size,
                              hipStream_t stream) {
  const float* x    = (const float*)d_in[0];
  const float* qkvw = (const float*)d_in[1];
  const float* qkvb = (const float*)d_in[2];
  const float* outw = (const float*)d_in[3];
  const float* outb = (const float*)d_in[4];
  float* out = (float*)d_out;

  unsigned char* ws = (unsigned char*)d_ws;
  u16* xb  = (u16*)(ws);                          // 12.58 MB  [8192][768] bf16
  u16* wqb = (u16*)(ws + 12582912);               //  3.54 MB  [2304][768] bf16
  u16* wob = (u16*)(ws + 16121856);               //  1.18 MB  [768][768]  bf16
  u16* Qbf = (u16*)(ws + 17301504);               // 12.58 MB  [96][1024][64]
  u16* Kbf = (u16*)(ws + 29884416);               // 12.58 MB  [96][1024][64]
  u16* Vtb = (u16*)(ws + 42467328);               // 12.58 MB  [96][64][1024]
  u16* Ob  = xb;                                  // reuse x region (dead after gemm1)

  cvt3_f32_bf16<<<dim3(2048), dim3(256), 0, stream>>>(
      x, xb, 8192 * 768 / 4, qkvw, wqb, 2304 * 768 / 4, outw, wob, 768 * 768 / 4);

  gemm_bt<128, 128, 4, 4, 1><<<dim3(1152), dim3(256), 0, stream>>>(
      xb, wqb, 8192, 2304, qkvb, nullptr, Qbf, Kbf, Vtb);

  attn_fwd<<<dim3(768), dim3(256), 0, stream>>>(Qbf, Kbf, Vtb, Ob);

  gemm_bt<128, 64, 4, 2, 0><<<dim3(768), dim3(256), 0, stream>>>(
      Ob, wob, 8192, 768, outb, out, nullptr, nullptr, nullptr);
}